// Round 3
// baseline (431.624 us; speedup 1.0000x reference)
//
#include <hip/hip_runtime.h>

// SpikingLayer scan: B=16, T=128, FEAT = 32*32*32 = 32768 floats.
// Layout in/out: [(b*T + t) * FEAT + f].
// One thread per float2 pair of neurons: 262,144 threads = 1024 blocks x 256
// = 4 blocks/CU = 16 waves/CU (4/SIMD). Serial scan over T with 8-deep
// ping-pong register prefetch: ~64 KB of loads in flight per CU, 8 B/lane
// vector access on both streams, nontemporal (pure stream, zero reuse).

typedef float f32x2 __attribute__((ext_vector_type(2)));

constexpr int T_STEPS = 128;
constexpr int FEAT    = 32 * 32 * 32;     // 32768
constexpr int FEAT2   = FEAT / 2;         // 16384 float2 per (b,t) plane
constexpr int CHUNK   = 8;
constexpr int NCHUNK  = T_STEPS / CHUNK;  // 16 (even)

__global__ __launch_bounds__(256) void spiking_scan_kernel(
    const f32x2* __restrict__ in, f32x2* __restrict__ out)
{
    const int idx = blockIdx.x * 256 + threadIdx.x;   // 0 .. 262143
    const int b   = idx >> 14;                        // idx / FEAT2
    const int f   = idx & (FEAT2 - 1);                // idx % FEAT2
    const size_t base = (size_t)b * T_STEPS * FEAT2 + (size_t)f;
    const f32x2* __restrict__ src = in  + base;
    f32x2*       __restrict__ dst = out + base;

    float s0 = 0.f, s1 = 0.f;   // membrane state
    float a0 = 0.f, a1 = 0.f;   // previous activation
    f32x2 bufA[CHUNK], bufB[CHUNK];

    // Reference FP op order, replicated exactly per element:
    //   state = (syn + state) - act
    //   state = max(state + 1, 0) - 1        (keep the +1/-1 round trip!)
    //   act   = max(floor(state), 0)         (== select; post-clamp s >= -1)
    #define STEP(buf, u, tt)                                            \
        do {                                                            \
            const f32x2 syn = buf[u];                                   \
            s0 = (syn.x + s0) - a0;                                     \
            s1 = (syn.y + s1) - a1;                                     \
            s0 = fmaxf(s0 + 1.0f, 0.0f) - 1.0f;                         \
            s1 = fmaxf(s1 + 1.0f, 0.0f) - 1.0f;                         \
            a0 = fmaxf(floorf(s0), 0.0f);                               \
            a1 = fmaxf(floorf(s1), 0.0f);                               \
            f32x2 o; o.x = a0; o.y = a1;                                \
            __builtin_nontemporal_store(o, &dst[(size_t)(tt) * FEAT2]); \
        } while (0)

    // prologue: chunk 0 -> bufA
    #pragma unroll
    for (int u = 0; u < CHUNK; ++u)
        bufA[u] = __builtin_nontemporal_load(&src[(size_t)u * FEAT2]);

    for (int c = 0; c < NCHUNK; c += 2) {
        // prefetch chunk c+1 -> bufB
        #pragma unroll
        for (int u = 0; u < CHUNK; ++u)
            bufB[u] = __builtin_nontemporal_load(
                &src[(size_t)((c + 1) * CHUNK + u) * FEAT2]);

        #pragma unroll
        for (int u = 0; u < CHUNK; ++u)
            STEP(bufA, u, c * CHUNK + u);

        // prefetch chunk c+2 -> bufA
        if (c + 2 < NCHUNK) {
            #pragma unroll
            for (int u = 0; u < CHUNK; ++u)
                bufA[u] = __builtin_nontemporal_load(
                    &src[(size_t)((c + 2) * CHUNK + u) * FEAT2]);
        }

        #pragma unroll
        for (int u = 0; u < CHUNK; ++u)
            STEP(bufB, u, (c + 1) * CHUNK + u);
    }
    #undef STEP
}

extern "C" void kernel_launch(void* const* d_in, const int* in_sizes, int n_in,
                              void* d_out, int out_size, void* d_ws, size_t ws_size,
                              hipStream_t stream)
{
    (void)in_sizes; (void)n_in; (void)d_ws; (void)ws_size; (void)out_size;
    const f32x2* in  = (const f32x2*)d_in[0];
    f32x2*       out = (f32x2*)d_out;

    // 16 * 16384 = 262144 threads = 1024 blocks of 256
    const int total = 16 * FEAT2;
    const int block = 256;
    const int grid  = total / block;   // 1024
    spiking_scan_kernel<<<grid, block, 0, stream>>>(in, out);
}